// Round 25
// baseline (57.757 us; speedup 1.0000x reference)
//
#include <hip/hip_runtime.h>

#define NN   2048
#define DD   64
#define KVB  32      // KV rows per tile
#define NTW  16      // tiles per wave (quarter KV axis: 512/32)
#define BH   32      // B*H
#define BHND (BH * NN * DD)
#define SC   0.18033688f     // 0.125 * log2(e): softmax in exp2 domain
#define TSH  4096            // shorts per fragment-packed tile (8 frags x 64 lanes x 8)

typedef float    f32x4  __attribute__((ext_vector_type(4)));
typedef short    bf16x8 __attribute__((ext_vector_type(8)));
typedef unsigned u32x4  __attribute__((ext_vector_type(4)));

#define WAIT_VM4()   asm volatile("s_waitcnt vmcnt(4)" ::: "memory")
#define SFENCE()     __builtin_amdgcn_sched_barrier(0)

__device__ __forceinline__ short f2bf(float x){
    unsigned u = __float_as_uint(x);
    u += 0x7FFF + ((u >> 16) & 1);      // round-to-nearest-even
    return (short)(u >> 16);
}

__device__ __forceinline__ unsigned cvt_pk(float lo, float hi){
    unsigned r;
    asm("v_cvt_pk_bf16_f32 %0, %1, %2" : "=v"(r) : "v"(lo), "v"(hi));
    return r;
}

__device__ __forceinline__ float exp2_fast(float x){
    float r;
    asm("v_exp_f32 %0, %1" : "=v"(r) : "v"(x));
    return r;
}

__device__ __forceinline__ void gload_lds16(const short* g, short* l) {
    __builtin_amdgcn_global_load_lds(
        (const __attribute__((address_space(1))) void*)g,
        (__attribute__((address_space(3))) void*)l, 16, 0, 0);
}

// ---------------- pre-pass: pack K,V into per-lane MFMA fragment order ----------------
// (v16's proven prep: 64 tiles of KVB=32 per bh; K frags 0..3, V frags at 2048+)
__global__ __launch_bounds__(256)
void prep_frag(const float* __restrict__ k, const float* __restrict__ v,
               short* __restrict__ fr)
{
    const int tile = blockIdx.x;         // 0..63
    const int bh   = blockIdx.y;
    const int tid  = threadIdx.x;
    const int lane = tid & 63;
    const int f    = tid >> 6;           // 0..3
    const int l16  = lane & 15;
    const int lg   = lane >> 4;
    const long base = (long)bh * NN * DD;
    const int  kv0  = tile * KVB;
    short* tb = fr + ((long)bh * 64 + tile) * TSH;

    // K fragment f = cb*2+c
    {
        const int cb = f >> 1, c = f & 1;
        const float* src = k + base + (long)(kv0 + cb * 16 + l16) * DD + c * 32 + lg * 8;
        f32x4 x0 = *(const f32x4*)src;
        f32x4 x1 = *(const f32x4*)(src + 4);
        bf16x8 o;
        #pragma unroll
        for (int j = 0; j < 4; ++j) { o[j] = f2bf(x0[j]); o[4 + j] = f2bf(x1[j]); }
        *(bf16x8*)(tb + (f * 64 + lane) * 8) = o;
    }
    // V fragment t2 = f (sigma-permuted rows)
    {
        const float* vb = v + base;
        bf16x8 o;
        #pragma unroll
        for (int i = 0; i < 8; ++i) {
            float x = vb[(long)(kv0 + (i >> 2) * 16 + lg * 4 + (i & 3)) * DD + f * 16 + l16];
            o[i] = f2bf(x);
        }
        *(bf16x8*)(tb + 2048 + (f * 64 + lane) * 8) = o;
    }
}

// ---------------- main fused attention v24 ----------------
// 1024 blocks x 4 waves: block = 64 q-rows, waves = 4 KV quarters with
// WAVE-PRIVATE K-only LDS streams (2 bufs x 4 KB each; 32 KB/block) and
// V fragments global->register. ZERO barriers in the main loop.
// 4 blocks/CU x 4 waves = 16 waves/CU = 4 waves/SIMD. No online max;
// ones-column row sums; 3-round additive in-LDS merge at the end.
__global__ __launch_bounds__(256, 2)
void attn_fwd_v24(const float* __restrict__ q,
                  const short* __restrict__ fr,
                  float* __restrict__ out)
{
    // bijective XCD swizzle: 4 bh per XCD
    const int l     = blockIdx.x;        // 0..1023
    const int xcd   = l & 7;
    const int idx   = l >> 3;            // 0..127
    const int qtile = idx & 31;          // 32 q-tiles of 64 rows per bh
    const int bh    = xcd + 8 * (idx >> 5);

    const int tid   = threadIdx.x;       // 0..255
    const int wave  = tid >> 6;          // 0..3 = KV quarter
    const int lane  = tid & 63;
    const int l16   = lane & 15;
    const int lg    = lane >> 4;

    __shared__ __align__(16) short k_lds[4][2][2048];  // [wave][buf] K-only: 32 KB

    const long base  = (long)bh * NN * DD;
    const int  qrow0 = qtile * 64;

    // ---- load Q (4 sub-blocks of 16 rows), convert with scale SC ----
    bf16x8 aq[4][2];
    #pragma unroll
    for (int j = 0; j < 4; ++j) {
        const float* qp = q + base + (long)(qrow0 + j * 16 + l16) * DD + lg * 8;
        #pragma unroll
        for (int c = 0; c < 2; ++c) {
            f32x4 x0 = *(const f32x4*)(qp + c * 32);
            f32x4 x1 = *(const f32x4*)(qp + c * 32 + 4);
            u32x4 pk;
            pk[0] = cvt_pk(x0[0] * SC, x0[1] * SC);
            pk[1] = cvt_pk(x0[2] * SC, x0[3] * SC);
            pk[2] = cvt_pk(x1[0] * SC, x1[1] * SC);
            pk[3] = cvt_pk(x1[2] * SC, x1[3] * SC);
            aq[j][c] = __builtin_bit_cast(bf16x8, pk);
        }
    }

    // ones B-fragment: PV with B=1 yields P row-sums in acc's exact lane layout
    bf16x8 ones;
    #pragma unroll
    for (int ii = 0; ii < 8; ++ii) ones[ii] = (short)0x3F80;

    // this wave's private quarter-stream: tiles [wave*16, wave*16+16)
    const short* fbase = fr + ((long)bh * 64 + wave * NTW) * TSH + lane * 8;

    auto stageK = [&](int buf, int tt) {
        const short* src = fbase + (long)tt * TSH;
        short* dst = &k_lds[wave][buf][0];
        #pragma unroll
        for (int j = 0; j < 4; ++j)
            gload_lds16(src + j * 512, dst + j * 512);
    };

    f32x4 acc[4][4];                      // [d-tile][sub-block]
    f32x4 accS[4];                        // row-sum tile per sub-block
    #pragma unroll
    for (int t = 0; t < 4; ++t)
        #pragma unroll
        for (int j = 0; j < 4; ++j) acc[t][j] = f32x4{0.f, 0.f, 0.f, 0.f};
    #pragma unroll
    for (int j = 0; j < 4; ++j) accS[j] = f32x4{0.f, 0.f, 0.f, 0.f};

    stageK(0, 0);

    #pragma unroll 1
    for (int t = 0; t < NTW; ++t) {
        // V fragments for tile t: global->register (newest 4 vmem ops)
        const short* vsrc = fbase + (long)t * TSH;
        bf16x8 bvv[4];
        #pragma unroll
        for (int t2 = 0; t2 < 4; ++t2)
            bvv[t2] = *(const bf16x8*)(vsrc + 2048 + t2 * 512);

        // drain to 4 outstanding: stageK(t) (the 4 oldest) complete; V(t) may fly
        SFENCE(); WAIT_VM4(); SFENCE();

        const short* lb = &k_lds[wave][t & 1][lane * 8];
        bf16x8 ka[2][2];
        #pragma unroll
        for (int cb = 0; cb < 2; ++cb)
            #pragma unroll
            for (int c = 0; c < 2; ++c)
                ka[cb][c] = *(const bf16x8*)(lb + (cb * 2 + c) * 512);

        // ---- swapped QK^T: s[cb][j] = S[q=j*16+l16][kv = cb*16 + lg*4 + r] ----
        f32x4 s[2][4];
        __builtin_amdgcn_s_setprio(1);
        #pragma unroll
        for (int cb = 0; cb < 2; ++cb)
            #pragma unroll
            for (int j = 0; j < 4; ++j) {
                f32x4 z = f32x4{0.f, 0.f, 0.f, 0.f};
                z = __builtin_amdgcn_mfma_f32_16x16x32_bf16(ka[cb][0], aq[j][0], z, 0, 0, 0);
                z = __builtin_amdgcn_mfma_f32_16x16x32_bf16(ka[cb][1], aq[j][1], z, 0, 0, 0);
                s[cb][j] = z;
            }
        __builtin_amdgcn_s_setprio(0);

        // stage K(t+1) into the other buffer (wave-private; t-1 reads long done)
        if (t + 1 < NTW) stageK((t + 1) & 1, t + 1);

        // ---- p = exp2(s); pack to bf16 (no VALU sum chain) ----
        bf16x8 pa[4];
        #pragma unroll
        for (int j = 0; j < 4; ++j) {
            #pragma unroll
            for (int cb = 0; cb < 2; ++cb)
                #pragma unroll
                for (int r = 0; r < 4; ++r)
                    s[cb][j][r] = exp2_fast(s[cb][j][r]);
            u32x4 w;
            w[0] = cvt_pk(s[0][j][0], s[0][j][1]);
            w[1] = cvt_pk(s[0][j][2], s[0][j][3]);
            w[2] = cvt_pk(s[1][j][0], s[1][j][1]);
            w[3] = cvt_pk(s[1][j][2], s[1][j][3]);
            pa[j] = __builtin_bit_cast(bf16x8, w);
        }

        // ---- PV (4 d-tiles) + ones-tile (compiler inserts V-load waits) ----
        __builtin_amdgcn_s_setprio(1);
        #pragma unroll
        for (int t2 = 0; t2 < 4; ++t2)
            #pragma unroll
            for (int j = 0; j < 4; ++j)
                acc[t2][j] = __builtin_amdgcn_mfma_f32_16x16x32_bf16(pa[j], bvv[t2], acc[t2][j], 0, 0, 0);
        #pragma unroll
        for (int j = 0; j < 4; ++j)
            accS[j] = __builtin_amdgcn_mfma_f32_16x16x32_bf16(pa[j], ones, accS[j], 0, 0, 0);
        __builtin_amdgcn_s_setprio(0);
    }

    // ---- 3-round additive merge across the 4 KV-quarter waves ----
    __syncthreads();                           // all staging traffic done; reuse LDS

    float* slot = (float*)&k_lds[0][0][0];     // 8192 floats; slot uses 5120
    #pragma unroll
    for (int r = 1; r <= 3; ++r) {
        if (wave == r) {
            #pragma unroll
            for (int t2 = 0; t2 < 4; ++t2)
                #pragma unroll
                for (int j = 0; j < 4; ++j)
                    *(f32x4*)&slot[((t2 * 4 + j) * 64 + lane) * 4] = acc[t2][j];
            #pragma unroll
            for (int j = 0; j < 4; ++j)
                *(f32x4*)&slot[((16 + j) * 64 + lane) * 4] = accS[j];
        }
        __syncthreads();
        if (wave == 0) {
            #pragma unroll
            for (int t2 = 0; t2 < 4; ++t2)
                #pragma unroll
                for (int j = 0; j < 4; ++j)
                    acc[t2][j] += *(const f32x4*)&slot[((t2 * 4 + j) * 64 + lane) * 4];
            #pragma unroll
            for (int j = 0; j < 4; ++j)
                accS[j] += *(const f32x4*)&slot[((16 + j) * 64 + lane) * 4];
        }
        __syncthreads();
    }

    if (wave == 0) {
        float* op = out + base + (long)qrow0 * DD;
        #pragma unroll
        for (int j = 0; j < 4; ++j) {
            f32x4 inv;
            #pragma unroll
            for (int r = 0; r < 4; ++r) inv[r] = 1.f / accS[j][r];
            #pragma unroll
            for (int t2 = 0; t2 < 4; ++t2)
                #pragma unroll
                for (int r = 0; r < 4; ++r)
                    op[(long)(j * 16 + lg * 4 + r) * DD + t2 * 16 + l16] = acc[t2][j][r] * inv[r];
        }
    }
}

extern "C" void kernel_launch(void* const* d_in, const int* in_sizes, int n_in,
                              void* d_out, int out_size, void* d_ws, size_t ws_size,
                              hipStream_t stream) {
    const float* q = (const float*)d_in[0];
    const float* k = (const float*)d_in[1];
    const float* v = (const float*)d_in[2];
    float* out = (float*)d_out;

    short* fr = (short*)d_ws;                 // BH * 64 tiles * 4096 shorts = 16 MB
    prep_frag<<<dim3(64, BH), 256, 0, stream>>>(k, v, fr);
    attn_fwd_v24<<<1024, 256, 0, stream>>>(q, fr, out);
    (void)ws_size;
}

// Round 26
// 51.766 us; speedup vs baseline: 1.1157x; 1.1157x over previous
//
#include <hip/hip_runtime.h>

#define NN   2048
#define DD   64
#define NTW  8       // super-iterations per wave (half KV / 128)
#define BH   32      // B*H
#define BHND (BH * NN * DD)
#define SC   0.18033688f     // 0.125 * log2(e): softmax in exp2 domain
#define TSH  8192            // shorts per packed 64-row tile (16 frags x 64 lanes x 8)

typedef float    f32x4  __attribute__((ext_vector_type(4)));
typedef short    bf16x8 __attribute__((ext_vector_type(8)));
typedef unsigned u32x4  __attribute__((ext_vector_type(4)));

#define WAIT_VM0()   asm volatile("s_waitcnt vmcnt(0)" ::: "memory")
#define SFENCE()     __builtin_amdgcn_sched_barrier(0)
#define SBAR()       __builtin_amdgcn_s_barrier()

__device__ __forceinline__ short f2bf(float x){
    unsigned u = __float_as_uint(x);
    u += 0x7FFF + ((u >> 16) & 1);      // round-to-nearest-even
    return (short)(u >> 16);
}

__device__ __forceinline__ unsigned cvt_pk(float lo, float hi){
    unsigned r;
    asm("v_cvt_pk_bf16_f32 %0, %1, %2" : "=v"(r) : "v"(lo), "v"(hi));
    return r;
}

__device__ __forceinline__ float exp2_fast(float x){
    float r;
    asm("v_exp_f32 %0, %1" : "=v"(r) : "v"(x));
    return r;
}

__device__ __forceinline__ void gload_lds16(const short* g, short* l) {
    __builtin_amdgcn_global_load_lds(
        (const __attribute__((address_space(1))) void*)g,
        (__attribute__((address_space(3))) void*)l, 16, 0, 0);
}

// ---------------- pre-pass: pack K,V into per-lane MFMA fragment order ----------------
// 64-row tile (8192 shorts): frags 0..7 = K (cb*2+c, cb=0..3), frags 8..15 = V (8+t2*2+kk).
__global__ __launch_bounds__(256)
void prep_frag(const float* __restrict__ k, const float* __restrict__ v,
               short* __restrict__ fr)
{
    const int tile = blockIdx.x;         // 0..31
    const int bh   = blockIdx.y;
    const int tid  = threadIdx.x;
    const int lane = tid & 63;
    const int f    = tid >> 6;           // 0..3
    const int l16  = lane & 15;
    const int lg   = lane >> 4;
    const long base = (long)bh * NN * DD;
    const int  kv0  = tile * 64;
    short* tb = fr + ((long)bh * 32 + tile) * TSH;

    // two K fragments: cb = f, c = 0 and 1 (one 64-col row read)
    {
        const float* src = k + base + (long)(kv0 + f * 16 + l16) * DD + lg * 8;
        #pragma unroll
        for (int c = 0; c < 2; ++c) {
            f32x4 x0 = *(const f32x4*)(src + c * 32);
            f32x4 x1 = *(const f32x4*)(src + c * 32 + 4);
            bf16x8 o;
            #pragma unroll
            for (int j = 0; j < 4; ++j) { o[j] = f2bf(x0[j]); o[4 + j] = f2bf(x1[j]); }
            *(bf16x8*)(tb + ((f * 2 + c) * 64 + lane) * 8) = o;
        }
    }
    // two V fragments: t2 = f, kk = 0 and 1 (sigma-permuted rows)
    {
        const float* vb = v + base;
        #pragma unroll
        for (int kk = 0; kk < 2; ++kk) {
            bf16x8 o;
            #pragma unroll
            for (int i = 0; i < 8; ++i) {
                float x = vb[(long)(kv0 + kk * 32 + (i >> 2) * 16 + lg * 4 + (i & 3)) * DD
                             + f * 16 + l16];
                o[i] = f2bf(x);
            }
            *(bf16x8*)(tb + ((8 + f * 2 + kk) * 64 + lane) * 8) = o;
        }
    }
}

// ---------------- main fused attention v25 ----------------
// v21 geometry (512 blocks x 4 waves = 2 qg x 2 kvh) but KVB=128: each of 8
// super-iterations consumes TWO 64-row subtiles. K-only LDS (2x2x16 KB=64 KB,
// staged cooperatively by the qg pair), V fragments global->register per
// subtile. ONE barrier + ONE vmcnt drain per 128 kv rows (half of v21's).
__global__ __launch_bounds__(256, 2)
void attn_fwd_v25(const float* __restrict__ q,
                  const short* __restrict__ fr,
                  float* __restrict__ out)
{
    // bijective XCD swizzle: 4 bh per XCD
    const int l     = blockIdx.x;        // 0..511
    const int xcd   = l & 7;
    const int idx   = l >> 3;            // 0..63
    const int qtile = idx & 15;          // 16 q-tiles of 128 rows per bh
    const int bh    = xcd + 8 * (idx >> 4);

    const int tid   = threadIdx.x;       // 0..255
    const int wave  = tid >> 6;          // 0..3
    const int qg    = wave & 1;          // q-group
    const int kvh   = wave >> 1;         // KV half
    const int lane  = tid & 63;
    const int l16   = lane & 15;
    const int lg    = lane >> 4;

    // K-only streams: [kv half][buf][2 subtiles x 8 frags x 512] = 64 KB
    __shared__ __align__(16) short k_lds[2][2][8192];

    const long base  = (long)bh * NN * DD;
    const int  qrow0 = qtile * 128 + qg * 64;

    // ---- load Q (4 sub-blocks of 16 rows), convert with scale SC ----
    bf16x8 aq[4][2];
    #pragma unroll
    for (int j = 0; j < 4; ++j) {
        const float* qp = q + base + (long)(qrow0 + j * 16 + l16) * DD + lg * 8;
        #pragma unroll
        for (int c = 0; c < 2; ++c) {
            f32x4 x0 = *(const f32x4*)(qp + c * 32);
            f32x4 x1 = *(const f32x4*)(qp + c * 32 + 4);
            u32x4 pk;
            pk[0] = cvt_pk(x0[0] * SC, x0[1] * SC);
            pk[1] = cvt_pk(x0[2] * SC, x0[3] * SC);
            pk[2] = cvt_pk(x1[0] * SC, x1[1] * SC);
            pk[3] = cvt_pk(x1[2] * SC, x1[3] * SC);
            aq[j][c] = __builtin_bit_cast(bf16x8, pk);
        }
    }

    // ones B-fragment: PV with B=1 yields P row-sums in acc's exact lane layout
    bf16x8 ones;
    #pragma unroll
    for (int ii = 0; ii < 8; ++ii) ones[ii] = (short)0x3F80;

    // this KV-half's 64-row-tile stream (16 subtiles); super-iter t = subtiles 2t,2t+1
    const short* fbase = fr + ((long)bh * 32 + kvh * 16) * TSH + lane * 8;

    // stage K of both subtiles of super-iter tt; qg pair splits the 16 K-frags
    auto stageK = [&](int buf, int tt) {
        const short* s0 = fbase + (long)(2 * tt) * TSH + qg * 4 * 512;
        const short* s1 = fbase + (long)(2 * tt + 1) * TSH + qg * 4 * 512;
        short* d0 = &k_lds[kvh][buf][qg * 4 * 512];
        short* d1 = &k_lds[kvh][buf][4096 + qg * 4 * 512];
        #pragma unroll
        for (int j = 0; j < 4; ++j) gload_lds16(s0 + j * 512, d0 + j * 512);
        #pragma unroll
        for (int j = 0; j < 4; ++j) gload_lds16(s1 + j * 512, d1 + j * 512);
    };

    f32x4 acc[4][4];                      // [d-tile][sub-block]
    f32x4 accS[4];                        // row-sum tile per sub-block
    #pragma unroll
    for (int t = 0; t < 4; ++t)
        #pragma unroll
        for (int j = 0; j < 4; ++j) acc[t][j] = f32x4{0.f, 0.f, 0.f, 0.f};
    #pragma unroll
    for (int j = 0; j < 4; ++j) accS[j] = f32x4{0.f, 0.f, 0.f, 0.f};

    stageK(0, 0);

    #pragma unroll 1
    for (int t = 0; t < NTW; ++t) {
        // my stageK(t) loads drained (V loads of t-1 already waited), barrier:
        // K super-tile t fully resident for both qg waves
        WAIT_VM0(); SFENCE();
        SBAR(); SFENCE();
        // stage K(t+1) into the buffer last read at t-1 (safe post-barrier)
        if (t + 1 < NTW) stageK((t + 1) & 1, t + 1);

        // ---- 4 halves: u = subtile (0,1), kk = cb-pair within subtile ----
        #pragma unroll
        for (int u = 0; u < 2; ++u) {
            const short* lb   = &k_lds[kvh][t & 1][u * 4096 + lane * 8];
            const short* vsrc = fbase + (long)(2 * t + u) * TSH;

            #pragma unroll
            for (int kk = 0; kk < 2; ++kk) {
                // V fragments for this half: global->register (latency hidden
                // under this half's QK+exp; compiler inserts the waits)
                bf16x8 bvv[4];
                #pragma unroll
                for (int t2 = 0; t2 < 4; ++t2)
                    bvv[t2] = *(const bf16x8*)(vsrc + (8 + t2 * 2 + kk) * 512);

                bf16x8 ka[2][2];
                #pragma unroll
                for (int cb = 0; cb < 2; ++cb)
                    #pragma unroll
                    for (int c = 0; c < 2; ++c)
                        ka[cb][c] = *(const bf16x8*)(lb + (((2 * kk + cb) * 2 + c)) * 512);

                // swapped QK^T: s[cb][j] = S[q=j*16+l16][kv = (2kk+cb)*16 + lg*4 + r]
                f32x4 s[2][4];
                __builtin_amdgcn_s_setprio(1);
                #pragma unroll
                for (int cb = 0; cb < 2; ++cb)
                    #pragma unroll
                    for (int j = 0; j < 4; ++j) {
                        f32x4 z = f32x4{0.f, 0.f, 0.f, 0.f};
                        z = __builtin_amdgcn_mfma_f32_16x16x32_bf16(ka[cb][0], aq[j][0], z, 0, 0, 0);
                        z = __builtin_amdgcn_mfma_f32_16x16x32_bf16(ka[cb][1], aq[j][1], z, 0, 0, 0);
                        s[cb][j] = z;
                    }
                __builtin_amdgcn_s_setprio(0);

                // p = exp2(s); pack; PV (+ ones row-sum)
                bf16x8 pa[4];
                #pragma unroll
                for (int j = 0; j < 4; ++j) {
                    #pragma unroll
                    for (int cb = 0; cb < 2; ++cb)
                        #pragma unroll
                        for (int r = 0; r < 4; ++r)
                            s[cb][j][r] = exp2_fast(s[cb][j][r]);
                    u32x4 w;
                    w[0] = cvt_pk(s[0][j][0], s[0][j][1]);
                    w[1] = cvt_pk(s[0][j][2], s[0][j][3]);
                    w[2] = cvt_pk(s[1][j][0], s[1][j][1]);
                    w[3] = cvt_pk(s[1][j][2], s[1][j][3]);
                    pa[j] = __builtin_bit_cast(bf16x8, w);
                }

                __builtin_amdgcn_s_setprio(1);
                #pragma unroll
                for (int t2 = 0; t2 < 4; ++t2)
                    #pragma unroll
                    for (int j = 0; j < 4; ++j)
                        acc[t2][j] = __builtin_amdgcn_mfma_f32_16x16x32_bf16(pa[j], bvv[t2], acc[t2][j], 0, 0, 0);
                #pragma unroll
                for (int j = 0; j < 4; ++j)
                    accS[j] = __builtin_amdgcn_mfma_f32_16x16x32_bf16(pa[j], ones, accS[j], 0, 0, 0);
                __builtin_amdgcn_s_setprio(0);
            }
        }
    }

    // ---- additive merge with partner wave (wave ^ 2), then normalize ----
    __syncthreads();                           // all staging traffic done; reuse LDS

    float* slot = (float*)&k_lds[0][0][0];     // 2 slots x 5120 floats (20 KB each)
    if (kvh == 1) {
        float* sp = slot + qg * 5120;
        #pragma unroll
        for (int t2 = 0; t2 < 4; ++t2)
            #pragma unroll
            for (int j = 0; j < 4; ++j)
                *(f32x4*)&sp[((t2 * 4 + j) * 64 + lane) * 4] = acc[t2][j];
        #pragma unroll
        for (int j = 0; j < 4; ++j)
            *(f32x4*)&sp[((16 + j) * 64 + lane) * 4] = accS[j];
    }
    __syncthreads();

    if (kvh == 0) {
        const float* sp = slot + qg * 5120;
        #pragma unroll
        for (int j = 0; j < 4; ++j)
            accS[j] += *(const f32x4*)&sp[((16 + j) * 64 + lane) * 4];
        float* op = out + base + (long)qrow0 * DD;
        #pragma unroll
        for (int j = 0; j < 4; ++j) {
            f32x4 inv;
            #pragma unroll
            for (int r = 0; r < 4; ++r) inv[r] = 1.f / accS[j][r];
            #pragma unroll
            for (int t2 = 0; t2 < 4; ++t2) {
                f32x4 o = acc[t2][j] + *(const f32x4*)&sp[((t2 * 4 + j) * 64 + lane) * 4];
                #pragma unroll
                for (int r = 0; r < 4; ++r)
                    op[(long)(j * 16 + lg * 4 + r) * DD + t2 * 16 + l16] = o[r] * inv[r];
            }
        }
    }
}

extern "C" void kernel_launch(void* const* d_in, const int* in_sizes, int n_in,
                              void* d_out, int out_size, void* d_ws, size_t ws_size,
                              hipStream_t stream) {
    const float* q = (const float*)d_in[0];
    const float* k = (const float*)d_in[1];
    const float* v = (const float*)d_in[2];
    float* out = (float*)d_out;

    short* fr = (short*)d_ws;                 // BH * 32 tiles * 8192 shorts = 16 MB
    prep_frag<<<dim3(32, BH), 256, 0, stream>>>(k, v, fr);
    attn_fwd_v25<<<512, 256, 0, stream>>>(q, fr, out);
    (void)ws_size;
}